// Round 8
// baseline (181.383 us; speedup 1.0000x reference)
//
#include <hip/hip_runtime.h>

#define NN 1024
#define NP (NN * NN)
#define NBLK 1024
#define NWAVE (NBLK * 4)      // 4096 waves, 16 pairs/tile -> 65536 tiles, 16 iters

typedef float f32x4 __attribute__((ext_vector_type(4)));
typedef __fp16 h2 __attribute__((ext_vector_type(2)));
typedef __fp16 h8 __attribute__((ext_vector_type(8)));

__device__ __forceinline__ f32x4 ntld(const float* p) {
  return __builtin_nontemporal_load((const f32x4*)p);
}

// ---------------- k1: LN+GEMV via MFMA -------------------------------------
// Per 16-pair tile (one wave): acc1 = A(x,f16)·B1 where B1 cols 0-5 = gamma*W,
// col 6 = ones (row-sum s); acc2 = A(x^2)·B2 (col 0 = ones -> q).
// x_d = rstd*(g_d - mu*Acol_d) + Bcol_d;  mu=s/128, var=q/128-mu^2.
__global__ __launch_bounds__(256) void k_ln_gemv(
    const float* __restrict__ pairp, const float* __restrict__ gamma,
    const float* __restrict__ beta, const float* __restrict__ W,
    const float* __restrict__ bvec, float* __restrict__ xout)
{
  const int lane = threadIdx.x & 63;
  const int wv = threadIdx.x >> 6;
  const int col = lane & 15;   // A-row / B-col / D-col
  const int g4 = lane >> 4;    // k-group (8 k's each)

  // B1 fragments per chunk c: B1[k][col], k = c*32 + g4*8 + i
  h8 B1[4];
  h8 B2;
#pragma unroll
  for (int c = 0; c < 4; ++c)
#pragma unroll
    for (int i = 0; i < 8; ++i) {
      const int k = c * 32 + g4 * 8 + i;
      float v = 0.f;
      if (col < 6) v = gamma[k] * W[k * 6 + col];
      else if (col == 6) v = 1.f;
      B1[c][i] = (__fp16)v;
      if (c == 0) B2[i] = (col == 0) ? (__fp16)1.f : (__fp16)0.f;
    }

  // Per-col LN-fold constants: Acol = sum gamma*W[:,col], Bcol = sum beta*W + b
  float Acol = 0.f, Bcol = 0.f;
  if (col < 6) {
    for (int c = 0; c < 128; ++c) {
      const float w = W[c * 6 + col];
      Acol = fmaf(gamma[c], w, Acol);
      Bcol = fmaf(beta[c], w, Bcol);
    }
    Bcol += bvec[col];
  }

  int tile = blockIdx.x * 4 + wv;
  // lane loads pair (tile*16+col), channels g4*8 + {0..7} (+32c)
  f32x4 L[8];
  {
    const float* base = pairp + (size_t)(tile * 16 + col) * 128 + g4 * 8;
#pragma unroll
    for (int c = 0; c < 4; ++c) {
      L[2 * c] = ntld(base + c * 32);
      L[2 * c + 1] = ntld(base + c * 32 + 4);
    }
  }

  for (int it = 0; it < 16; ++it) {
    // convert current tile to f16 fragments (+ squared)
    h8 A[4], A2[4];
#pragma unroll
    for (int c = 0; c < 4; ++c) {
      const h2 p0 = __builtin_amdgcn_cvt_pkrtz(L[2 * c].x, L[2 * c].y);
      const h2 p1 = __builtin_amdgcn_cvt_pkrtz(L[2 * c].z, L[2 * c].w);
      const h2 p2 = __builtin_amdgcn_cvt_pkrtz(L[2 * c + 1].x, L[2 * c + 1].y);
      const h2 p3 = __builtin_amdgcn_cvt_pkrtz(L[2 * c + 1].z, L[2 * c + 1].w);
      A[c][0] = p0.x; A[c][1] = p0.y; A[c][2] = p1.x; A[c][3] = p1.y;
      A[c][4] = p2.x; A[c][5] = p2.y; A[c][6] = p3.x; A[c][7] = p3.y;
      A2[c] = A[c] * A[c];
    }

    // prefetch next tile while MFMA/epilogue run
    const int ntile = tile + NWAVE;
    if (it != 15) {
      const float* nb = pairp + (size_t)(ntile * 16 + col) * 128 + g4 * 8;
#pragma unroll
      for (int c = 0; c < 4; ++c) {
        L[2 * c] = ntld(nb + c * 32);
        L[2 * c + 1] = ntld(nb + c * 32 + 4);
      }
    }

    f32x4 acc1 = {0.f, 0.f, 0.f, 0.f};
    f32x4 acc2 = {0.f, 0.f, 0.f, 0.f};
#pragma unroll
    for (int c = 0; c < 4; ++c) {
      acc1 = __builtin_amdgcn_mfma_f32_16x16x32_f16(A[c], B1[c], acc1, 0, 0, 0);
      acc2 = __builtin_amdgcn_mfma_f32_16x16x32_f16(A2[c], B2, acc2, 0, 0, 0);
    }

    // epilogue: lane holds D[4*g4+m][col]; s in col 6 (acc1), q in col 0 (acc2)
    const int src_s = (lane & 48) + 6;
    const int src_q = (lane & 48);
#pragma unroll
    for (int m = 0; m < 4; ++m) {
      const float s = __shfl(acc1[m], src_s);
      const float q = __shfl(acc2[m], src_q);
      const float mu = s * (1.f / 128.f);
      const float var = q * (1.f / 128.f) - mu * mu;
      const float rstd = rsqrtf(var + 1e-5f);
      const float o = fmaf(rstd, acc1[m] - mu * Acol, Bcol);
      if (col < 6) xout[(size_t)(tile * 16 + 4 * g4 + m) * 6 + col] = o;
    }
    tile = ntile;
  }
}

// ---------------- k_sym: one-shot tiled symmetrize + mask + rowsum -----------
__global__ __launch_bounds__(256) void k_sym(
    const float* __restrict__ x, const int* __restrict__ seq,
    float* __restrict__ xs, float* __restrict__ rowsum)
{
  const int J = blockIdx.x, I = blockIdx.y;
  const int tid = threadIdx.x;
  __shared__ float M[32 * 193];

  const float* mb = x + ((size_t)(J * 32) * NN + I * 32) * 6;
  for (int k = tid; k < 1536; k += 256) {
    const int m = k / 48, f = k % 48;
    const float4 v = *(const float4*)(mb + (size_t)m * (NN * 6) + f * 4);
    float* dst = &M[m * 193 + f * 4];
    dst[0] = v.x; dst[1] = v.y; dst[2] = v.z; dst[3] = v.w;
  }
  __syncthreads();

  float es[4][6];
#pragma unroll
  for (int q = 0; q < 4; ++q) {
    const int e = tid + 256 * q;
    const int r = e >> 5, c = e & 31;
    const int i = I * 32 + r, j = J * 32 + c;
    const int dd = seq[i] - seq[j];
    const bool far = (dd > 3) || (dd < -3);
    const float* own = x + ((size_t)i * NN + j) * 6;
    const float2 o0 = *(const float2*)(own);
    const float2 o1 = *(const float2*)(own + 2);
    const float2 o2 = *(const float2*)(own + 4);
    const float* mr = &M[c * 193 + r * 6];
    float v[6];
    v[0] = far ? 0.5f * (o0.x + mr[0]) : -1000000.f;
    v[1] = far ? 0.5f * (o0.y + mr[1]) : -1000000.f;
    v[2] = far ? 0.5f * (o1.x + mr[2]) : -1000000.f;
    v[3] = far ? 0.5f * (o1.y + mr[3]) : -1000000.f;
    v[4] = far ? 0.5f * (o2.x + mr[4]) : -1000000.f;
    v[5] = far ? 0.5f * (o2.y + mr[5]) : -1000000.f;
    float* op = xs + ((size_t)i * NN + j) * 6;
    *(float2*)(op) = make_float2(v[0], v[1]);
    *(float2*)(op + 2) = make_float2(v[2], v[3]);
    *(float2*)(op + 4) = make_float2(v[4], v[5]);
#pragma unroll
    for (int d = 0; d < 6; ++d) es[q][d] = __expf(v[d]);
  }

#pragma unroll
  for (int q = 0; q < 4; ++q)
#pragma unroll
    for (int d = 0; d < 6; ++d)
#pragma unroll
      for (int m = 1; m <= 16; m <<= 1) es[q][d] += __shfl_xor(es[q][d], m);

  if ((tid & 31) == 0) {
    const int w = tid >> 5;
#pragma unroll
    for (int q = 0; q < 4; ++q) {
      const int i = I * 32 + w + 8 * q;
#pragma unroll
      for (int d = 0; d < 6; ++d) atomicAdd(&rowsum[i * 6 + d], es[q][d]);
    }
  }
}

__global__ __launch_bounds__(256) void k_lse(
    const float* __restrict__ rowsum, float* __restrict__ lse)
{
  const int k = blockIdx.x * 256 + threadIdx.x;
  if (k < NN * 6) lse[k] = logf(1.0f + rowsum[k]);
}

__global__ __launch_bounds__(256) void k_out(
    float* __restrict__ out, const float* __restrict__ lse)
{
  const int p = blockIdx.x * 256 + threadIdx.x;
  const int i = p >> 10;
  const int j = p & (NN - 1);

  float* a = out + (size_t)p * 6;
  const float2 a0 = *(const float2*)(a);
  const float2 a1 = *(const float2*)(a + 2);
  const float2 a2 = *(const float2*)(a + 4);
  const float v[6] = {a0.x, a0.y, a1.x, a1.y, a2.x, a2.y};

  float ssum = 0.f;
#pragma unroll
  for (int d = 0; d < 6; ++d) ssum += __expf(v[d]);
  const float lc2 = 2.f * logf(1.f + ssum);

  const float* li = lse + i * 6;
  const float* lj = lse + j * 6;
  float o[6];
#pragma unroll
  for (int d = 0; d < 6; ++d) o[d] = 4.f * v[d] - li[d] - lj[d] - lc2;

  *(float2*)(a) = make_float2(o[0], o[1]);
  *(float2*)(a + 2) = make_float2(o[2], o[3]);
  *(float2*)(a + 4) = make_float2(o[4], o[5]);
}

extern "C" void kernel_launch(void* const* d_in, const int* in_sizes, int n_in,
                              void* d_out, int out_size, void* d_ws, size_t ws_size,
                              hipStream_t stream) {
  const float* pairp = (const float*)d_in[0];
  const int* seq = (const int*)d_in[1];
  const float* gamma = (const float*)d_in[2];
  const float* beta = (const float*)d_in[3];
  const float* W = (const float*)d_in[4];
  const float* bvec = (const float*)d_in[5];
  float* out = (float*)d_out;

  float* x = (float*)d_ws;              // raw x: 1024*1024*6 fp32 = 24 MB
  float* rowsum = x + (size_t)NP * 6;   // 1024*6
  float* lse = rowsum + NN * 6;         // 1024*6

  (void)hipMemsetAsync(rowsum, 0, NN * 6 * sizeof(float), stream);
  k_ln_gemv<<<NBLK, 256, 0, stream>>>(pairp, gamma, beta, W, bvec, x);
  k_sym<<<dim3(32, 32), 256, 0, stream>>>(x, seq, out, rowsum);  // xs -> out
  k_lse<<<(NN * 6 + 255) / 256, 256, 0, stream>>>(rowsum, lse);
  k_out<<<NP / 256, 256, 0, stream>>>(out, lse);
}

// Round 9
// 171.075 us; speedup vs baseline: 1.0603x; 1.0603x over previous
//
#include <hip/hip_runtime.h>

#define NN 1024
#define NP (NN * NN)
#define NBLK 1024
#define NWAVE (NBLK * 4)      // 4096 waves; 65536 tiles of 16 pairs; 16 iters

typedef float f32x4 __attribute__((ext_vector_type(4)));
typedef __fp16 h2 __attribute__((ext_vector_type(2)));
typedef __fp16 h4 __attribute__((ext_vector_type(4)));
typedef __fp16 h8 __attribute__((ext_vector_type(8)));

__device__ __forceinline__ h8 pack8(h2 a, h2 b, h2 c, h2 d) {
  h4 ab = __builtin_shufflevector(a, b, 0, 1, 2, 3);
  h4 cd = __builtin_shufflevector(c, d, 0, 1, 2, 3);
  return __builtin_shufflevector(ab, cd, 0, 1, 2, 3, 4, 5, 6, 7);
}

// ---------------- k1: LN+GEMV via MFMA (v2) ---------------------------------
// acc[d] = sum_k x_k * (gamma_k W_kd - Acol_d/128) = g_d - mu*Acol_d
// x_d = rstd * acc[d] + Bcol_d;  s,q computed per-lane in f32 from raw loads.
// Lane (col,g4) holds pair (tile*16+col), k-chunk {4g4..+3, 16+4g4..+3} per c.
__global__ __launch_bounds__(256) void k_ln_gemv(
    const float* __restrict__ pairp, const float* __restrict__ gamma,
    const float* __restrict__ beta, const float* __restrict__ W,
    const float* __restrict__ bvec, float* __restrict__ xout)
{
  const int lane = threadIdx.x & 63;
  const int wv = threadIdx.x >> 6;
  const int col = lane & 15;
  const int g4 = lane >> 4;

  // Per-col constants: Acol = sum gamma*W[:,col], Bcol = sum beta*W + b
  float Acol = 0.f, Bcol = 0.f;
  if (col < 6) {
    for (int c = 0; c < 128; ++c) {
      const float w = W[c * 6 + col];
      Acol = fmaf(gamma[c], w, Acol);
      Bcol = fmaf(beta[c], w, Bcol);
    }
    Bcol += bvec[col];
  }

  // B fragments with LN fold (cols 6..15 zero)
  h8 B1[4];
#pragma unroll
  for (int c = 0; c < 4; ++c)
#pragma unroll
    for (int i = 0; i < 8; ++i) {
      const int kl = (i < 4) ? (4 * g4 + i) : (16 + 4 * g4 + (i - 4));
      const int k = c * 32 + kl;
      float v = 0.f;
      if (col < 6) v = fmaf(gamma[k], W[k * 6 + col], -Acol * (1.f / 128.f));
      B1[c][i] = (__fp16)v;
    }

  const int src_base = (lane & 48) + 4 * g4;  // rstd source lane for row 4*g4+m

  int tile = blockIdx.x * 4 + wv;
  f32x4 L[8];
  {
    const float* base = pairp + (size_t)(tile * 16 + col) * 128 + 4 * g4;
#pragma unroll
    for (int c = 0; c < 4; ++c) {
      L[2 * c] = *(const f32x4*)(base + c * 32);
      L[2 * c + 1] = *(const f32x4*)(base + c * 32 + 16);
    }
  }

  for (int it = 0; it < 16; ++it) {
    // convert to f16 fragments + f32 stats from current tile
    h8 A[4];
    float s = 0.f, q = 0.f;
#pragma unroll
    for (int c = 0; c < 4; ++c) {
      const f32x4 u = L[2 * c], v = L[2 * c + 1];
      A[c] = pack8(__builtin_amdgcn_cvt_pkrtz(u.x, u.y),
                   __builtin_amdgcn_cvt_pkrtz(u.z, u.w),
                   __builtin_amdgcn_cvt_pkrtz(v.x, v.y),
                   __builtin_amdgcn_cvt_pkrtz(v.z, v.w));
      s += ((u.x + u.y) + (u.z + u.w)) + ((v.x + v.y) + (v.z + v.w));
      q = fmaf(u.x, u.x, fmaf(u.y, u.y, fmaf(u.z, u.z, fmaf(u.w, u.w, q))));
      q = fmaf(v.x, v.x, fmaf(v.y, v.y, fmaf(v.z, v.z, fmaf(v.w, v.w, q))));
    }

    // prefetch next tile (plain loads; L2 merges companion half-lines)
    const int ntile = tile + NWAVE;
    if (it != 15) {
      const float* nb = pairp + (size_t)(ntile * 16 + col) * 128 + 4 * g4;
#pragma unroll
      for (int c = 0; c < 4; ++c) {
        L[2 * c] = *(const f32x4*)(nb + c * 32);
        L[2 * c + 1] = *(const f32x4*)(nb + c * 32 + 16);
      }
    }

    // per-pair stats: reduce over the 4 k-chunk lanes (same col)
    s += __shfl_xor(s, 16); s += __shfl_xor(s, 32);
    q += __shfl_xor(q, 16); q += __shfl_xor(q, 32);
    const float mu = s * (1.f / 128.f);
    const float var = q * (1.f / 128.f) - mu * mu;
    const float rstd = rsqrtf(var + 1e-5f);  // for pair tile*16+col

    f32x4 acc = {0.f, 0.f, 0.f, 0.f};
#pragma unroll
    for (int c = 0; c < 4; ++c)
      acc = __builtin_amdgcn_mfma_f32_16x16x32_f16(A[c], B1[c], acc, 0, 0, 0);

    // epilogue: lane holds D[4*g4+m][col]; fetch that row's rstd, fma, store
#pragma unroll
    for (int m = 0; m < 4; ++m) {
      const float rs = __shfl(rstd, src_base + m);
      const float o = fmaf(rs, acc[m], Bcol);
      if (col < 6) xout[(size_t)(tile * 16 + 4 * g4 + m) * 6 + col] = o;
    }
    tile = ntile;
  }
}

// ---------------- k_sym: one-shot tiled symmetrize + mask + rowsum -----------
__global__ __launch_bounds__(256) void k_sym(
    const float* __restrict__ x, const int* __restrict__ seq,
    float* __restrict__ xs, float* __restrict__ rowsum)
{
  const int J = blockIdx.x, I = blockIdx.y;
  const int tid = threadIdx.x;
  __shared__ float M[32 * 193];

  const float* mb = x + ((size_t)(J * 32) * NN + I * 32) * 6;
  for (int k = tid; k < 1536; k += 256) {
    const int m = k / 48, f = k % 48;
    const float4 v = *(const float4*)(mb + (size_t)m * (NN * 6) + f * 4);
    float* dst = &M[m * 193 + f * 4];
    dst[0] = v.x; dst[1] = v.y; dst[2] = v.z; dst[3] = v.w;
  }
  __syncthreads();

  float es[4][6];
#pragma unroll
  for (int q = 0; q < 4; ++q) {
    const int e = tid + 256 * q;
    const int r = e >> 5, c = e & 31;
    const int i = I * 32 + r, j = J * 32 + c;
    const int dd = seq[i] - seq[j];
    const bool far = (dd > 3) || (dd < -3);
    const float* own = x + ((size_t)i * NN + j) * 6;
    const float2 o0 = *(const float2*)(own);
    const float2 o1 = *(const float2*)(own + 2);
    const float2 o2 = *(const float2*)(own + 4);
    const float* mr = &M[c * 193 + r * 6];
    float v[6];
    v[0] = far ? 0.5f * (o0.x + mr[0]) : -1000000.f;
    v[1] = far ? 0.5f * (o0.y + mr[1]) : -1000000.f;
    v[2] = far ? 0.5f * (o1.x + mr[2]) : -1000000.f;
    v[3] = far ? 0.5f * (o1.y + mr[3]) : -1000000.f;
    v[4] = far ? 0.5f * (o2.x + mr[4]) : -1000000.f;
    v[5] = far ? 0.5f * (o2.y + mr[5]) : -1000000.f;
    float* op = xs + ((size_t)i * NN + j) * 6;
    *(float2*)(op) = make_float2(v[0], v[1]);
    *(float2*)(op + 2) = make_float2(v[2], v[3]);
    *(float2*)(op + 4) = make_float2(v[4], v[5]);
#pragma unroll
    for (int d = 0; d < 6; ++d) es[q][d] = __expf(v[d]);
  }

#pragma unroll
  for (int q = 0; q < 4; ++q)
#pragma unroll
    for (int d = 0; d < 6; ++d)
#pragma unroll
      for (int m = 1; m <= 16; m <<= 1) es[q][d] += __shfl_xor(es[q][d], m);

  if ((tid & 31) == 0) {
    const int w = tid >> 5;
#pragma unroll
    for (int q = 0; q < 4; ++q) {
      const int i = I * 32 + w + 8 * q;
#pragma unroll
      for (int d = 0; d < 6; ++d) atomicAdd(&rowsum[i * 6 + d], es[q][d]);
    }
  }
}

__global__ __launch_bounds__(256) void k_lse(
    const float* __restrict__ rowsum, float* __restrict__ lse)
{
  const int k = blockIdx.x * 256 + threadIdx.x;
  if (k < NN * 6) lse[k] = logf(1.0f + rowsum[k]);
}

__global__ __launch_bounds__(256) void k_out(
    float* __restrict__ out, const float* __restrict__ lse)
{
  const int p = blockIdx.x * 256 + threadIdx.x;
  const int i = p >> 10;
  const int j = p & (NN - 1);

  float* a = out + (size_t)p * 6;
  const float2 a0 = *(const float2*)(a);
  const float2 a1 = *(const float2*)(a + 2);
  const float2 a2 = *(const float2*)(a + 4);
  const float v[6] = {a0.x, a0.y, a1.x, a1.y, a2.x, a2.y};

  float ssum = 0.f;
#pragma unroll
  for (int d = 0; d < 6; ++d) ssum += __expf(v[d]);
  const float lc2 = 2.f * logf(1.f + ssum);

  const float* li = lse + i * 6;
  const float* lj = lse + j * 6;
  float o[6];
#pragma unroll
  for (int d = 0; d < 6; ++d) o[d] = 4.f * v[d] - li[d] - lj[d] - lc2;

  *(float2*)(a) = make_float2(o[0], o[1]);
  *(float2*)(a + 2) = make_float2(o[2], o[3]);
  *(float2*)(a + 4) = make_float2(o[4], o[5]);
}

extern "C" void kernel_launch(void* const* d_in, const int* in_sizes, int n_in,
                              void* d_out, int out_size, void* d_ws, size_t ws_size,
                              hipStream_t stream) {
  const float* pairp = (const float*)d_in[0];
  const int* seq = (const int*)d_in[1];
  const float* gamma = (const float*)d_in[2];
  const float* beta = (const float*)d_in[3];
  const float* W = (const float*)d_in[4];
  const float* bvec = (const float*)d_in[5];
  float* out = (float*)d_out;

  float* x = (float*)d_ws;              // raw x: 1024*1024*6 fp32 = 24 MB
  float* rowsum = x + (size_t)NP * 6;   // 1024*6
  float* lse = rowsum + NN * 6;         // 1024*6

  (void)hipMemsetAsync(rowsum, 0, NN * 6 * sizeof(float), stream);
  k_ln_gemv<<<NBLK, 256, 0, stream>>>(pairp, gamma, beta, W, bvec, x);
  k_sym<<<dim3(32, 32), 256, 0, stream>>>(x, seq, out, rowsum);  // xs -> out
  k_lse<<<(NN * 6 + 255) / 256, 256, 0, stream>>>(rowsum, lse);
  k_out<<<NP / 256, 256, 0, stream>>>(out, lse);
}